// Round 6
// baseline (98.031 us; speedup 1.0000x reference)
//
#include <hip/hip_runtime.h>

#define NQ 10

typedef float v2f __attribute__((ext_vector_type(2)));

__device__ __forceinline__ int   f2i(float v) { union { float f; int i; } u; u.f = v; return u.i; }
__device__ __forceinline__ float i2f(int v)   { union { int i; float f; } u; u.i = v; return u.f; }

__device__ __forceinline__ v2f cmul(v2f a, v2f b) {
    return (v2f){ fmaf(a.x, b.x, -a.y * b.y), fmaf(a.x, b.y, a.y * b.x) };
}

template<int C> __device__ __forceinline__ int dppm(int v) {
    return __builtin_amdgcn_mov_dpp(v, C, 0xF, 0xF, false);
}

// ---- VOP3P packed complex helpers (verified R3-R5) ----
template<int SP> __device__ __forceinline__ v2f pk_mul_sel(v2f a, v2f K) {
    v2f d;
    if constexpr (SP == 0)
        asm("v_pk_mul_f32 %0, %1, %2 op_sel:[0,0] op_sel_hi:[1,0]" : "=v"(d) : "v"(a), "v"(K));
    else
        asm("v_pk_mul_f32 %0, %1, %2 op_sel:[0,1] op_sel_hi:[1,1]" : "=v"(d) : "v"(a), "v"(K));
    return d;
}
template<int SP> __device__ __forceinline__ v2f pk_fma_sel(v2f a, v2f K, v2f c) {
    v2f d;
    if constexpr (SP == 0)
        asm("v_pk_fma_f32 %0, %1, %2, %3 op_sel:[0,0,0] op_sel_hi:[1,0,1]"
            : "=v"(d) : "v"(a), "v"(K), "v"(c));
    else
        asm("v_pk_fma_f32 %0, %1, %2, %3 op_sel:[0,1,0] op_sel_hi:[1,1,1]"
            : "=v"(d) : "v"(a), "v"(K), "v"(c));
    return d;
}
template<int SP> __device__ __forceinline__ v2f pk_fma_i_sel(v2f a, v2f K, v2f c) {
    v2f d;
    if constexpr (SP == 0)
        asm("v_pk_fma_f32 %0, %1, %2, %3 op_sel:[1,0,0] op_sel_hi:[0,0,1] neg_lo:[1,0,0]"
            : "=v"(d) : "v"(a), "v"(K), "v"(c));
    else
        asm("v_pk_fma_f32 %0, %1, %2, %3 op_sel:[1,1,0] op_sel_hi:[0,1,1] neg_lo:[1,0,0]"
            : "=v"(d) : "v"(a), "v"(K), "v"(c));
    return d;
}

// ---- lane exchange by xor mask (verified R5) ----
template<int LM>
__device__ __forceinline__ v2f xlane(v2f v, int baddr) {
    if constexpr (LM == 0) return v;
    int x = f2i(v.x), y = f2i(v.y);
    if constexpr (LM == 1)       { x = dppm<177>(x);            y = dppm<177>(y); }
    else if constexpr (LM == 2)  { x = dppm<78>(x);             y = dppm<78>(y); }
    else if constexpr (LM == 3)  { x = dppm<27>(x);             y = dppm<27>(y); }
    else if constexpr (LM == 4)  { x = dppm<321>(dppm<27>(x));  y = dppm<321>(dppm<27>(y)); }
    else if constexpr (LM == 6)  { x = dppm<321>(dppm<177>(x)); y = dppm<321>(dppm<177>(y)); }
    else if constexpr (LM == 8)  { x = dppm<320>(dppm<321>(x)); y = dppm<320>(dppm<321>(y)); }
    else if constexpr (LM == 12) { x = dppm<320>(dppm<27>(x));  y = dppm<320>(dppm<27>(y)); }
    else if constexpr (LM < 32) {
        constexpr int off = (LM << 10) | 0x1F;
        x = __builtin_amdgcn_ds_swizzle(x, off);
        y = __builtin_amdgcn_ds_swizzle(y, off);
    } else {
        x = __builtin_amdgcn_ds_bpermute(baddr, x);
        y = __builtin_amdgcn_ds_bpermute(baddr, y);
    }
    return (v2f){ i2f(x), i2f(y) };
}

struct Kset { v2f Ar, Ai, Br, Bi; };

__device__ __forceinline__ Kset build_K(float4 r0, float4 r1, float cq, float sq, int lp)
{
    const float g00r = fmaf(r0.x, cq,  r0.z * sq), g00i = fmaf(r0.y, cq,  r0.w * sq);
    const float g01r = fmaf(r0.z, cq, -r0.x * sq), g01i = fmaf(r0.w, cq, -r0.y * sq);
    const float g10r = fmaf(r1.x, cq,  r1.z * sq), g10i = fmaf(r1.y, cq,  r1.w * sq);
    const float g11r = fmaf(r1.z, cq, -r1.x * sq), g11i = fmaf(r1.w, cq, -r1.y * sq);
    Kset K;
    K.Ar = lp ? (v2f){g11r, g00r} : (v2f){g00r, g11r};
    K.Ai = lp ? (v2f){g11i, g00i} : (v2f){g00i, g11i};
    K.Br = lp ? (v2f){g10r, g01r} : (v2f){g01r, g10r};
    K.Bi = lp ? (v2f){g10i, g01i} : (v2f){g01i, g10i};
    return K;
}

#define QNN_FMA8                                                              \
    QNN_F(0) QNN_F(1) QNN_F(2) QNN_F(3) QNN_F(4) QNN_F(5) QNN_F(6) QNN_F(7)
#define QNN_F(J) { constexpr int SP_ = __builtin_popcount((J) & RJ) & 1;      \
    v2f t_ = pk_mul_sel<SP_>(a[J], K.Ar);                                     \
    t_ = pk_fma_i_sel<SP_>(a[J], K.Ai, t_);                                   \
    t_ = pk_fma_sel<SP_>(o[J], K.Br, t_);                                     \
    t_ = pk_fma_i_sel<SP_>(o[J], K.Bi, t_);                                   \
    a[J] = t_; }

// in-wave gate: slot-xor JM, lane-xor LM; parity (RJ slot, RL lane, RW wave)
template<int JM, int LM, int RJ, int RL, int RW>
__device__ __forceinline__ void gate_in(v2f (&a)[8], float4 r0, float4 r1,
                                        float cq, float sq, int lane, int wv)
{
    int lp = 0;
    if constexpr (RL != 0) lp = __popc(lane & RL) & 1;
    if constexpr (RW != 0) lp ^= wv;
    const Kset K = build_K(r0, r1, cq, sq, lp);
    const int baddr = ((lane ^ LM) << 2);
    v2f o[8];
    #pragma unroll
    for (int j = 0; j < 8; ++j) o[j] = xlane<LM>(a[j ^ JM], baddr);
    QNN_FMA8
}

// wave-crossing gate: stage slot-major in LDS (8B stride => free 2-way)
template<int JM, int LM, int RJ, int RL, int RW>
__device__ __forceinline__ void gate_st(v2f (&a)[8], v2f* stage, float4 r0, float4 r1,
                                        float cq, float sq, int t, int lane, int wv)
{
    int lp = 0;
    if constexpr (RL != 0) lp = __popc(lane & RL) & 1;
    if constexpr (RW != 0) lp ^= wv;
    const Kset K = build_K(r0, r1, cq, sq, lp);
    #pragma unroll
    for (int j = 0; j < 8; ++j) stage[j * 256 + t] = a[j];
    __syncthreads();
    const int pt = t ^ 64 ^ LM;           // flip wave bit (bit 6 of tid) + lane xor
    v2f o[8];
    #pragma unroll
    for (int j = 0; j < 8; ++j) o[j] = stage[(j ^ JM) * 256 + pt];
    __syncthreads();
    QNN_FMA8
}

// Physical layout: bits0-2 slot j, bits3-8 lane, bit9 wave (=total logical parity).
// Basis: s0={01} s1={12} s2={23} l0={34} l1={45} l2={56} l3={67} l4={78} l5={89}
// w={0,1,9}. All gate/measurement masks below derived from the R2-verified
// logical (C,R) table via c=coords(C), r=B^T R.
__global__ __launch_bounds__(256, 6)
void qnn_kernel(const float* __restrict__ x, const float* __restrict__ w,
                float* __restrict__ out)
{
    __shared__ float4 rotL[3 * NQ][2];
    __shared__ v2f    stage[2048];        // 16 KB: [slot][tid]
    __shared__ float  zred[2][2][NQ];

    const int t    = threadIdx.x;
    const int lane = t & 63;
    const int wv   = (t >> 6) & 1;        // physical bit 9
    const int el   = t >> 7;              // element within block
    const int b    = blockIdx.x * 2 + el;

    if (t < 3 * NQ) {
        const float* wp = w + t * 3;
        float phi = wp[0], th = wp[1], om = wp[2];
        float ct = cosf(th * 0.5f), st = sinf(th * 0.5f);
        float ap = (phi + om) * 0.5f, am = (phi - om) * 0.5f;
        float cap = cosf(ap), sap = sinf(ap);
        float cam = cosf(am), sam = sinf(am);
        rotL[t][0] = make_float4(cap * ct, -sap * ct, -cam * st, -sam * st);
        rotL[t][1] = make_float4(cam * st, -sam * st,  cap * ct,  sap * ct);
    }
    __syncthreads();

    // per-batch RY cos/sin (wave-uniform -> SGPRs)
    const float* xb = x + (size_t)__builtin_amdgcn_readfirstlane(b * NQ);
    float c_[NQ], s_[NQ];
    #pragma unroll
    for (int q = 0; q < NQ; ++q) {
        float xv = xb[q] * 0.5f;
        c_[q] = i2f(__builtin_amdgcn_readfirstlane(f2i(__cosf(xv))));
        s_[q] = i2f(__builtin_amdgcn_readfirstlane(f2i(__sinf(xv))));
    }

    // ---- layer 1 analytic product state ----
    // logical bits at physical (j0..2, l0..5, wv):
    // b0=j0^wv b1=j0^j1^wv b2=j1^j2 b3=j2^L0 b4=L0^L1 b5=L1^L2 b6=L2^L3
    // b7=L3^L4 b8=L4^L5 b9=L5^wv
    v2f g0v[2], g1v[2], g2v[2], g3v[2], F;
    {
        v2f g[NQ][2];
        #pragma unroll
        for (int q = 0; q < NQ; ++q) {
            const float4 r0 = rotL[q][0], r1 = rotL[q][1];
            const float cq = c_[q], sq = s_[q];
            g[q][0] = (v2f){ fmaf(r0.x, cq, r0.z * sq), fmaf(r0.y, cq, r0.w * sq) };
            g[q][1] = (v2f){ fmaf(r1.x, cq, r1.z * sq), fmaf(r1.y, cq, r1.w * sq) };
        }
        const int L0 = lane & 1, L1 = (lane >> 1) & 1, L2 = (lane >> 2) & 1;
        const int L3 = (lane >> 3) & 1, L4 = (lane >> 4) & 1, L5 = (lane >> 5) & 1;
        F = cmul(cmul(cmul(g[4][L0 ^ L1], g[5][L1 ^ L2]),
                      cmul(g[6][L2 ^ L3], g[7][L3 ^ L4])),
                 cmul(g[8][L4 ^ L5], g[9][L5 ^ wv]));
        g0v[0] = g[0][wv];     g0v[1] = g[0][1 ^ wv];       // index j0
        g1v[0] = g[1][wv];     g1v[1] = g[1][1 ^ wv];       // index j0^j1
        g2v[0] = g[2][0];      g2v[1] = g[2][1];            // index j1^j2
        g3v[0] = g[3][L0];     g3v[1] = g[3][1 ^ L0];       // index j2
    }
    v2f a[8];
    #pragma unroll
    for (int j = 0; j < 8; ++j) {
        const int j0 = j & 1, j1 = (j >> 1) & 1, j2 = (j >> 2) & 1;
        a[j] = cmul(cmul(cmul(g0v[j0], g1v[j0 ^ j1]),
                         cmul(g2v[j1 ^ j2], g3v[j2])), F);
    }

    // ---- layers 2..3: 20 gates in the new basis ----
#define GI(IDX, Q, JM, LM, RJ, RL, RW) \
    gate_in<JM, LM, RJ, RL, RW>(a, rotL[IDX][0], rotL[IDX][1], c_[Q], s_[Q], lane, wv);
#define GS(IDX, Q, JM, LM, RJ, RL, RW) \
    gate_st<JM, LM, RJ, RL, RW>(a, stage, rotL[IDX][0], rotL[IDX][1], c_[Q], s_[Q], t, lane, wv);
    GI(10, 0, 1,  0, 1,  0, 0)
    GI(11, 1, 2,  0, 2,  0, 0)
    GI(12, 2, 4,  0, 4,  0, 0)
    GI(13, 3, 0,  1, 0,  1, 0)
    GI(14, 4, 0,  2, 0,  2, 0)
    GI(15, 5, 0,  4, 0,  4, 0)
    GI(16, 6, 0,  8, 0,  8, 0)
    GI(17, 7, 0, 16, 0, 16, 0)
    GI(18, 8, 0, 32, 0, 32, 0)
    GS(19, 9, 0,  0, 0,  0, 1)          // pure wave swap
    GI(20, 0, 3,  0, 6, 63, 1)
    GI(21, 1, 6,  0, 3,  0, 0)
    GI(22, 2, 4,  1, 7,  0, 0)
    GI(23, 3, 0,  3, 7,  1, 0)
    GI(24, 4, 0,  6, 7,  3, 0)
    GI(25, 5, 0, 12, 7,  7, 0)
    GI(26, 6, 0, 24, 7, 15, 0)
    GI(27, 7, 0, 48, 7, 31, 0)
    GS(28, 8, 0, 32, 7, 63, 0)          // wave + lane32
    GS(29, 9, 3,  0, 7, 63, 1)          // wave + slot3
#undef GI
#undef GS

    // ---- probabilities + 3-bit Walsh-Hadamard over slots ----
    float P[8];
    #pragma unroll
    for (int j = 0; j < 8; ++j)
        P[j] = fmaf(a[j].x, a[j].x, a[j].y * a[j].y);
    #pragma unroll
    for (int bit = 0; bit < 3; ++bit) {
        #pragma unroll
        for (int j = 0; j < 8; ++j)
            if (!(j & (1 << bit))) {
                int k = j | (1 << bit);
                float u = P[j], v = P[k];
                P[j] = u + v;
                P[k] = u - v;
            }
    }

    const int bp32 = ((lane ^ 32) << 2);
    float vout = 0.f;
#define MEAS(Q, RJ_, RL_, RW_)                                                \
    { float v = P[RJ_];                                                       \
      int ng = __popc(lane & (RL_));                                          \
      if (RW_) ng ^= wv;                                                      \
      if (ng & 1) v = -v;                                                     \
      v += i2f(dppm<177>(f2i(v)));                                            \
      v += i2f(dppm<78>(f2i(v)));                                             \
      v += i2f(dppm<321>(dppm<27>(f2i(v))));                                  \
      v += i2f(dppm<320>(dppm<321>(f2i(v))));                                 \
      v += i2f(__builtin_amdgcn_ds_swizzle(f2i(v), (16 << 10) | 0x1F));       \
      v += i2f(__builtin_amdgcn_ds_bpermute(bp32, f2i(v)));                   \
      if (lane == (Q)) vout = v; }
    MEAS(0, 3, 21, 1) MEAS(1, 5, 63, 1) MEAS(2, 2, 63, 1) MEAS(3, 5, 62, 1)
    MEAS(4, 2, 61, 1) MEAS(5, 5, 58, 1) MEAS(6, 2, 53, 1) MEAS(7, 5, 42, 1)
    MEAS(8, 2, 21, 1) MEAS(9, 5, 42, 0)
#undef MEAS

    if (lane < NQ) zred[el][wv][lane] = vout;
    __syncthreads();
    if (wv == 0 && lane < NQ)
        out[b * NQ + lane] = zred[el][0][lane] + zred[el][1][lane];
}

extern "C" void kernel_launch(void* const* d_in, const int* in_sizes, int n_in,
                              void* d_out, int out_size, void* d_ws, size_t ws_size,
                              hipStream_t stream) {
    const float* x = (const float*)d_in[0];   // (4096, 10) f32
    const float* w = (const float*)d_in[1];   // (3, 10, 3) f32
    float* out = (float*)d_out;               // (4096, 10) f32
    const int B = in_sizes[0] / NQ;           // 4096
    qnn_kernel<<<B / 2, 256, 0, stream>>>(x, w, out);
}

// Round 7
// 78.597 us; speedup vs baseline: 1.2473x; 1.2473x over previous
//
#include <hip/hip_runtime.h>

#define NQ 10

typedef float v2f __attribute__((ext_vector_type(2)));

__device__ __forceinline__ int   f2i(float v) { union { float f; int i; } u; u.f = v; return u.i; }
__device__ __forceinline__ float i2f(int v)   { union { int i; float f; } u; u.i = v; return u.f; }

__device__ __forceinline__ v2f cmul(v2f a, v2f b) {
    return (v2f){ fmaf(a.x, b.x, -a.y * b.y), fmaf(a.x, b.y, a.y * b.x) };
}

template<int C> __device__ __forceinline__ int dppm(int v) {
    return __builtin_amdgcn_mov_dpp(v, C, 0xF, 0xF, false);
}

// ---- VOP3P packed complex helpers (verified R3-R5) ----
template<int SP> __device__ __forceinline__ v2f pk_mul_sel(v2f a, v2f K) {
    v2f d;
    if constexpr (SP == 0)
        asm("v_pk_mul_f32 %0, %1, %2 op_sel:[0,0] op_sel_hi:[1,0]" : "=v"(d) : "v"(a), "v"(K));
    else
        asm("v_pk_mul_f32 %0, %1, %2 op_sel:[0,1] op_sel_hi:[1,1]" : "=v"(d) : "v"(a), "v"(K));
    return d;
}
template<int SP> __device__ __forceinline__ v2f pk_fma_sel(v2f a, v2f K, v2f c) {
    v2f d;
    if constexpr (SP == 0)
        asm("v_pk_fma_f32 %0, %1, %2, %3 op_sel:[0,0,0] op_sel_hi:[1,0,1]"
            : "=v"(d) : "v"(a), "v"(K), "v"(c));
    else
        asm("v_pk_fma_f32 %0, %1, %2, %3 op_sel:[0,1,0] op_sel_hi:[1,1,1]"
            : "=v"(d) : "v"(a), "v"(K), "v"(c));
    return d;
}
template<int SP> __device__ __forceinline__ v2f pk_fma_i_sel(v2f a, v2f K, v2f c) {
    v2f d;
    if constexpr (SP == 0)
        asm("v_pk_fma_f32 %0, %1, %2, %3 op_sel:[1,0,0] op_sel_hi:[0,0,1] neg_lo:[1,0,0]"
            : "=v"(d) : "v"(a), "v"(K), "v"(c));
    else
        asm("v_pk_fma_f32 %0, %1, %2, %3 op_sel:[1,1,0] op_sel_hi:[0,1,1] neg_lo:[1,0,0]"
            : "=v"(d) : "v"(a), "v"(K), "v"(c));
    return d;
}

// ---- lane exchange by xor mask LM (all masks <32; element halves never mix:
// DPP row ops are 16-local, ds_swizzle BitMode is 32-group-local) ----
template<int LM>
__device__ __forceinline__ v2f xlane(v2f v) {
    if constexpr (LM == 0) return v;
    int x = f2i(v.x), y = f2i(v.y);
    if constexpr (LM == 1)       { x = dppm<177>(x);            y = dppm<177>(y); }
    else if constexpr (LM == 2)  { x = dppm<78>(x);             y = dppm<78>(y); }
    else if constexpr (LM == 3)  { x = dppm<27>(x);             y = dppm<27>(y); }
    else if constexpr (LM == 5)  { x = dppm<321>(dppm<78>(x));  y = dppm<321>(dppm<78>(y)); }
    else if constexpr (LM == 6)  { x = dppm<321>(dppm<177>(x)); y = dppm<321>(dppm<177>(y)); }
    else if constexpr (LM == 8)  { x = dppm<320>(dppm<321>(x)); y = dppm<320>(dppm<321>(y)); }
    else if constexpr (LM == 12) { x = dppm<320>(dppm<27>(x));  y = dppm<320>(dppm<27>(y)); }
    else {
        constexpr int off = (LM << 10) | 0x1F;   // BitMode xor within 32-lane group
        x = __builtin_amdgcn_ds_swizzle(x, off);
        y = __builtin_amdgcn_ds_swizzle(y, off);
    }
    return (v2f){ i2f(x), i2f(y) };
}

struct Kset { v2f Ar, Ai, Br, Bi; };

__device__ __forceinline__ Kset build_K(float4 r0, float4 r1, float cq, float sq, int lp)
{
    const float g00r = fmaf(r0.x, cq,  r0.z * sq), g00i = fmaf(r0.y, cq,  r0.w * sq);
    const float g01r = fmaf(r0.z, cq, -r0.x * sq), g01i = fmaf(r0.w, cq, -r0.y * sq);
    const float g10r = fmaf(r1.x, cq,  r1.z * sq), g10i = fmaf(r1.y, cq,  r1.w * sq);
    const float g11r = fmaf(r1.z, cq, -r1.x * sq), g11i = fmaf(r1.w, cq, -r1.y * sq);
    Kset K;
    K.Ar = lp ? (v2f){g11r, g00r} : (v2f){g00r, g11r};
    K.Ai = lp ? (v2f){g11i, g00i} : (v2f){g00i, g11i};
    K.Br = lp ? (v2f){g10r, g01r} : (v2f){g01r, g10r};
    K.Bi = lp ? (v2f){g10i, g01i} : (v2f){g01i, g10i};
    return K;
}

#define REP16(X, B) X(B) X(B|1) X(B|2) X(B|3) X(B|4) X(B|5) X(B|6) X(B|7) \
                    X(B|8) X(B|9) X(B|10) X(B|11) X(B|12) X(B|13) X(B|14) X(B|15)

// Gate on 32-slot register state. Slot xor JM, lane xor LM (within 32);
// parity: RJ over slot bits (compile-time per slot), RL over lane bits.
// JM<16: two 16-slot phases (batched exchange, bounded o-pressure; safe since
// phase-1 touches only slots [0,16)). JM>=16: pairwise orbits (low pressure).
template<int JM, int LM, int RJ, int RL>
__device__ __forceinline__ void gate(v2f (&a)[32], float4 r0, float4 r1,
                                     float cq, float sq, int lane)
{
    const int lp = (RL != 0) ? (__popc(lane & RL) & 1) : 0;
    const Kset K = build_K(r0, r1, cq, sq, lp);
#define QNN_F(J, O) { constexpr int SP_ = __builtin_popcount((J) & RJ) & 1;   \
        v2f t_ = pk_mul_sel<SP_>(a[J], K.Ar);                                 \
        t_ = pk_fma_i_sel<SP_>(a[J], K.Ai, t_);                               \
        t_ = pk_fma_sel<SP_>(O, K.Br, t_);                                    \
        t_ = pk_fma_i_sel<SP_>(O, K.Bi, t_);                                  \
        a[J] = t_; }
    if constexpr (JM < 16) {
        {
            v2f o[16];
#define QNN_E(J) o[(J) & 15] = xlane<LM>(a[(J) ^ JM]);
            REP16(QNN_E, 0)
#undef QNN_E
#define QNN_G(J) QNN_F(J, o[(J) & 15])
            REP16(QNN_G, 0)
#undef QNN_G
        }
        {
            v2f o[16];
#define QNN_E(J) o[(J) & 15] = xlane<LM>(a[(J) ^ JM]);
            REP16(QNN_E, 16)
#undef QNN_E
#define QNN_G(J) QNN_F(J, o[(J) & 15])
            REP16(QNN_G, 16)
#undef QNN_G
        }
    } else {
        constexpr int HB = 1 << (31 - __builtin_clz((unsigned)JM));
#define QNN_P(J) if constexpr (((J) & HB) == 0) {                             \
            constexpr int KP = (J) ^ JM;                                      \
            v2f oj = xlane<LM>(a[KP]);                                        \
            v2f ok = xlane<LM>(a[J]);                                         \
            QNN_F(J, oj)                                                      \
            QNN_F(KP, ok)                                                     \
        }
        REP16(QNN_P, 0)
        REP16(QNN_P, 16)
#undef QNN_P
    }
#undef QNN_F
}

// Layout: amp index = slot j (logical bits 0-4, 32 v2f regs) | lane5 (logical
// bits 5-9). Lane bit 5 = batch element (two elements per wave). All masks are
// the R2-verified logical masks split as JM=M&31, LM=M>>5, RJ=R&31, RL=R>>5.
__global__ __launch_bounds__(256, 2)
void qnn_kernel(const float* __restrict__ x, const float* __restrict__ w,
                float* __restrict__ out)
{
    __shared__ float4 rotL[3 * NQ][2];

    const int t    = threadIdx.x;
    const int lane = t & 63;
    const int l5   = lane & 31;
    const int b    = (blockIdx.x * 4 + (t >> 6)) * 2 + (lane >> 5);

    if (t < 3 * NQ) {
        const float* wp = w + t * 3;
        float phi = wp[0], th = wp[1], om = wp[2];
        float ct = cosf(th * 0.5f), st = sinf(th * 0.5f);
        float ap = (phi + om) * 0.5f, am = (phi - om) * 0.5f;
        float cap = cosf(ap), sap = sinf(ap);
        float cam = cosf(am), sam = sinf(am);
        rotL[t][0] = make_float4(cap * ct, -sap * ct, -cam * st, -sam * st);
        rotL[t][1] = make_float4(cam * st, -sam * st,  cap * ct,  sap * ct);
    }
    __syncthreads();

    // per-element RY cos/sin (uniform within each 32-lane half)
    const float* xb = x + (size_t)b * NQ;
    float c_[NQ], s_[NQ];
    #pragma unroll
    for (int q = 0; q < NQ; ++q) {
        float xv = xb[q] * 0.5f;
        c_[q] = __cosf(xv);
        s_[q] = __sinf(xv);
    }

    // ---- layer 1 analytic product state ----
    v2f a[32];
    {
        v2f g[NQ][2];
        #pragma unroll
        for (int q = 0; q < NQ; ++q) {
            const float4 r0 = rotL[q][0], r1 = rotL[q][1];
            g[q][0] = (v2f){ fmaf(r0.x, c_[q], r0.z * s_[q]),
                             fmaf(r0.y, c_[q], r0.w * s_[q]) };
            g[q][1] = (v2f){ fmaf(r1.x, c_[q], r1.z * s_[q]),
                             fmaf(r1.y, c_[q], r1.w * s_[q]) };
        }
        const v2f F = cmul(cmul(cmul(g[5][l5 & 1], g[6][(l5 >> 1) & 1]),
                                cmul(g[7][(l5 >> 2) & 1], g[8][(l5 >> 3) & 1])),
                           g[9][(l5 >> 4) & 1]);
        const v2f G4F[2] = { cmul(g[4][0], F), cmul(g[4][1], F) };
        v2f S01[4], S23[4];
        #pragma unroll
        for (int i = 0; i < 4; ++i) {
            S01[i] = cmul(g[0][i & 1], g[1][(i >> 1) & 1]);
            S23[i] = cmul(g[2][i & 1], g[3][(i >> 1) & 1]);
        }
        #pragma unroll
        for (int j = 0; j < 32; ++j)
            a[j] = cmul(cmul(S01[j & 3], S23[(j >> 2) & 3]), G4F[(j >> 4) & 1]);
    }

    // ---- layers 2..3: R2-verified masks, 5/5 slot/lane split ----
#define G(IDX, Q, JM, LM, RJ, RL) \
    gate<JM, LM, RJ, RL>(a, rotL[IDX][0], rotL[IDX][1], c_[Q], s_[Q], lane);
    G(10, 0,  3,  0, 0x1E, 0x1F)
    G(11, 1,  6,  0, 0x03, 0x00)
    G(12, 2, 12,  0, 0x07, 0x00)
    G(13, 3, 24,  0, 0x0F, 0x00)
    G(14, 4, 16,  1, 0x1F, 0x00)
    G(15, 5,  0,  3, 0x1F, 0x01)
    G(16, 6,  0,  6, 0x1F, 0x03)
    G(17, 7,  0, 12, 0x1F, 0x07)
    G(18, 8,  0, 24, 0x1F, 0x0F)
    G(19, 9,  3, 16, 0x1F, 0x1F)
    G(20, 0,  5,  0,   11,   21)
    G(21, 1, 10,  0,   29,   31)
    G(22, 2, 20,  0,   26,   31)
    G(23, 3,  8,  1,   21,   31)
    G(24, 4, 16,  2,   10,   31)
    G(25, 5,  0,  5,   21,   30)
    G(26, 6,  0, 10,   10,   29)
    G(27, 7,  0, 20,   21,   26)
    G(28, 8,  3,  8,   10,   21)
    G(29, 9,  6, 16,   21,   10)
#undef G

    // ---- probabilities + 5-bit Walsh-Hadamard over slots ----
    float P[32];
    #pragma unroll
    for (int j = 0; j < 32; ++j)
        P[j] = fmaf(a[j].x, a[j].x, a[j].y * a[j].y);
    #pragma unroll
    for (int bit = 0; bit < 5; ++bit) {
        #pragma unroll
        for (int j = 0; j < 32; ++j)
            if (!(j & (1 << bit))) {
                int k = j | (1 << bit);
                float u = P[j], v = P[k];
                P[j] = u + v;
                P[k] = u - v;
            }
    }

    // ---- <Z_q>: sign by lane parity, reduce within the 32-lane half ----
    float vout = 0.f;
#define MEAS(Q, RJ_, RL_)                                                     \
    { float v = P[RJ_];                                                       \
      if (__popc(lane & (RL_)) & 1) v = -v;                                   \
      v += i2f(dppm<177>(f2i(v)));                 /* xor1  */                \
      v += i2f(dppm<78>(f2i(v)));                  /* xor2  */                \
      v += i2f(dppm<321>(dppm<27>(f2i(v))));       /* xor4  */                \
      v += i2f(dppm<320>(dppm<321>(f2i(v))));      /* xor8  */                \
      v += i2f(__builtin_amdgcn_ds_swizzle(f2i(v), (16 << 10) | 0x1F));       \
      if (l5 == (Q)) vout = v; }
    MEAS(0, 13,  6) MEAS(1, 22, 10) MEAS(2, 12, 21) MEAS(3, 25, 10)
    MEAS(4, 19, 21) MEAS(5,  6, 11) MEAS(6, 12, 22) MEAS(7, 25, 12)
    MEAS(8, 19, 25) MEAS(9,  6, 19)
#undef MEAS

    if (l5 < NQ) out[(size_t)b * NQ + l5] = vout;
}

extern "C" void kernel_launch(void* const* d_in, const int* in_sizes, int n_in,
                              void* d_out, int out_size, void* d_ws, size_t ws_size,
                              hipStream_t stream) {
    const float* x = (const float*)d_in[0];   // (4096, 10) f32
    const float* w = (const float*)d_in[1];   // (3, 10, 3) f32
    float* out = (float*)d_out;               // (4096, 10) f32
    const int B = in_sizes[0] / NQ;           // 4096
    qnn_kernel<<<B / 8, 256, 0, stream>>>(x, w, out);  // 2 elements per wave
}

// Round 8
// 77.707 us; speedup vs baseline: 1.2616x; 1.0115x over previous
//
#include <hip/hip_runtime.h>

#define NQ 10
#define NL 3

typedef float v2f __attribute__((ext_vector_type(2)));

__device__ __forceinline__ int   f2i(float v) { union { float f; int i; } u; u.f = v; return u.i; }
__device__ __forceinline__ float i2f(int v)   { union { int i; float f; } u; u.i = v; return u.f; }

__device__ __forceinline__ v2f cmul(v2f a, v2f b) {
    return (v2f){ fmaf(a.x, b.x, -a.y * b.y), fmaf(a.x, b.y, a.y * b.x) };
}

template<int C> __device__ __forceinline__ int dppm(int v) {
    return __builtin_amdgcn_mov_dpp(v, C, 0xF, 0xF, false);
}

// ---- lane exchange by xor mask LM. Single-DPP only for LM 1,2,3 (2-cyc VALU,
// zero latency). Everything else goes to the DS pipe (swizzle <32, bpermute
// >=32) to keep VALU free for the FMA stream. ----
template<int LM>
__device__ __forceinline__ v2f xlane(v2f v, int baddr) {
    if constexpr (LM == 0) return v;
    int x = f2i(v.x), y = f2i(v.y);
    if constexpr (LM == 1)       { x = dppm<177>(x); y = dppm<177>(y); }
    else if constexpr (LM == 2)  { x = dppm<78>(x);  y = dppm<78>(y); }
    else if constexpr (LM == 3)  { x = dppm<27>(x);  y = dppm<27>(y); }
    else if constexpr (LM < 32) {
        constexpr int off = (LM << 10) | 0x1F;   // BitMode xor
        x = __builtin_amdgcn_ds_swizzle(x, off);
        y = __builtin_amdgcn_ds_swizzle(y, off);
    } else {
        x = __builtin_amdgcn_ds_bpermute(baddr, x);
        y = __builtin_amdgcn_ds_bpermute(baddr, y);
    }
    return (v2f){ i2f(x), i2f(y) };
}

// Generalized single-qubit gate under GF(2) index transform (masks verified
// R2-R5). Scalar v_fma_f32 math (8 FMA/amp, neg folded into operand
// modifiers); slot parity SP is compile-time so coefficient choice is free.
template<int MASK, int RMASK>
__device__ __forceinline__ void apply_gate(v2f (&a)[16], float4 r0, float4 r1,
                                           float cq, float sq, int lane)
{
    constexpr int LM = (MASK >> 4) & 63;
    constexpr int JM = MASK & 15;
    constexpr int RH = (RMASK >> 4) & 63;
    constexpr int RL = RMASK & 15;

    // fuse Rot * RY(c,s)
    const float g00r = fmaf(r0.x, cq,  r0.z * sq), g00i = fmaf(r0.y, cq,  r0.w * sq);
    const float g01r = fmaf(r0.z, cq, -r0.x * sq), g01i = fmaf(r0.w, cq, -r0.y * sq);
    const float g10r = fmaf(r1.x, cq,  r1.z * sq), g10i = fmaf(r1.y, cq,  r1.w * sq);
    const float g11r = fmaf(r1.z, cq, -r1.x * sq), g11i = fmaf(r1.w, cq, -r1.y * sq);

    const bool lp = (RH != 0) && (__popc(lane & RH) & 1);
    // parity-0 (total parity even) and parity-1 coefficient sets
    const float A0r = lp ? g11r : g00r, A0i = lp ? g11i : g00i;
    const float B0r = lp ? g10r : g01r, B0i = lp ? g10i : g01i;
    const float A1r = lp ? g00r : g11r, A1i = lp ? g00i : g11i;
    const float B1r = lp ? g01r : g10r, B1i = lp ? g01i : g10i;

    const int baddr = ((lane ^ LM) << 2);

    // phase 1: all partner values (independent -> batched DS/DPP issue)
    v2f o[16];
    #pragma unroll
    for (int j = 0; j < 16; ++j) o[j] = xlane<LM>(a[j ^ JM], baddr);

    // phase 2: 8 scalar FMAs per amp; new = A*a + B*o (complex)
#define QNN_F(J) { constexpr int SP_ = __builtin_popcount((J) & RL) & 1;      \
    const float Ar = SP_ ? A1r : A0r, Ai = SP_ ? A1i : A0i;                   \
    const float Br = SP_ ? B1r : B0r, Bi = SP_ ? B1i : B0i;                   \
    const float ar = a[J].x, ai = a[J].y, pr = o[J].x, pi = o[J].y;           \
    float re = ar * Ar;       re = fmaf(-Ai, ai, re);                         \
    re = fmaf(Br, pr, re);    re = fmaf(-Bi, pi, re);                         \
    float im = ai * Ar;       im = fmaf(Ai, ar, im);                          \
    im = fmaf(Br, pi, im);    im = fmaf(Bi, pr, im);                          \
    a[J] = (v2f){re, im}; }
    QNN_F(0) QNN_F(1) QNN_F(2) QNN_F(3) QNN_F(4) QNN_F(5) QNN_F(6) QNN_F(7)
    QNN_F(8) QNN_F(9) QNN_F(10) QNN_F(11) QNN_F(12) QNN_F(13) QNN_F(14) QNN_F(15)
#undef QNN_F
}

__global__ __launch_bounds__(256, 4)
void qnn_kernel(const float* __restrict__ x, const float* __restrict__ w,
                float* __restrict__ out)
{
    __shared__ float4 rotL[NL * NQ][2];   // (R00,R01) | (R10,R11)

    const int t    = threadIdx.x;
    const int lane = t & 63;
    const int b    = blockIdx.x * 4 + (t >> 6);   // one wave per batch element

    if (t < NL * NQ) {
        const float* wp = w + t * 3;
        float phi = wp[0], th = wp[1], om = wp[2];
        float ct = cosf(th * 0.5f), st = sinf(th * 0.5f);
        float ap = (phi + om) * 0.5f, am = (phi - om) * 0.5f;
        float cap = cosf(ap), sap = sinf(ap);
        float cam = cosf(am), sam = sinf(am);
        rotL[t][0] = make_float4(cap * ct, -sap * ct, -cam * st, -sam * st);
        rotL[t][1] = make_float4(cam * st, -sam * st,  cap * ct,  sap * ct);
    }
    __syncthreads();

    // ---- per-batch RY cos/sin (wave-uniform -> SGPR via readfirstlane) ----
    const float* xb = x + (size_t)__builtin_amdgcn_readfirstlane(b * NQ);
    float c_[NQ], s_[NQ];
    #pragma unroll
    for (int q = 0; q < NQ; ++q) {
        float xv = xb[q] * 0.5f;
        c_[q] = i2f(__builtin_amdgcn_readfirstlane(f2i(__cosf(xv))));
        s_[q] = i2f(__builtin_amdgcn_readfirstlane(f2i(__sinf(xv))));
    }

    // ---- layer 1 analytic: product state amp[p] = prod_q col0(G_q)[bit_q(p)] ----
    v2f c0[4], c1[4];
    v2f Ln = {1.f, 0.f};
    #pragma unroll
    for (int q = 0; q < NQ; ++q) {
        float4 r0 = rotL[q][0], r1 = rotL[q][1];
        float cq = c_[q], sq = s_[q];
        v2f g0 = { fmaf(r0.x, cq, r0.z * sq), fmaf(r0.y, cq, r0.w * sq) };
        v2f g1 = { fmaf(r1.x, cq, r1.z * sq), fmaf(r1.y, cq, r1.w * sq) };
        if (q < 4) { c0[q] = g0; c1[q] = g1; }
        else {
            v2f gg = ((lane >> (q - 4)) & 1) ? g1 : g0;
            Ln = (q == 4) ? gg : cmul(Ln, gg);
        }
    }
    v2f S01[4], SH[4];
    #pragma unroll
    for (int j = 0; j < 4; ++j)
        S01[j] = cmul((j & 1) ? c1[0] : c0[0], (j & 2) ? c1[1] : c0[1]);
    #pragma unroll
    for (int h = 0; h < 4; ++h)
        SH[h] = cmul(cmul((h & 1) ? c1[2] : c0[2], (h & 2) ? c1[3] : c0[3]), Ln);
    v2f a[16];
    #pragma unroll
    for (int j = 0; j < 16; ++j)
        a[j] = cmul(S01[j & 3], SH[j >> 2]);

    // ---- layers 2..3 (masks + parities verified in R2/R3/R5) ----
#define GATE(IDX, Q, MASK, RMASK) \
    apply_gate<MASK, RMASK>(a, rotL[IDX][0], rotL[IDX][1], c_[Q], s_[Q], lane);
    GATE(10, 0, 0x003, 0x3FE)  GATE(11, 1, 0x006, 0x003)
    GATE(12, 2, 0x00C, 0x007)  GATE(13, 3, 0x018, 0x00F)
    GATE(14, 4, 0x030, 0x01F)  GATE(15, 5, 0x060, 0x03F)
    GATE(16, 6, 0x0C0, 0x07F)  GATE(17, 7, 0x180, 0x0FF)
    GATE(18, 8, 0x300, 0x1FF)  GATE(19, 9, 0x203, 0x3FF)
    GATE(20, 0, 0x005, 0x2AB)  GATE(21, 1, 0x00A, 0x3FD)
    GATE(22, 2, 0x014, 0x3FA)  GATE(23, 3, 0x028, 0x3F5)
    GATE(24, 4, 0x050, 0x3EA)  GATE(25, 5, 0x0A0, 0x3D5)
    GATE(26, 6, 0x140, 0x3AA)  GATE(27, 7, 0x280, 0x355)
    GATE(28, 8, 0x103, 0x2AA)  GATE(29, 9, 0x206, 0x155)
#undef GATE

    // ---- probabilities + 4-bit Walsh-Hadamard over slots ----
    float P[16];
    #pragma unroll
    for (int j = 0; j < 16; ++j)
        P[j] = fmaf(a[j].x, a[j].x, a[j].y * a[j].y);
    #pragma unroll
    for (int bit = 0; bit < 4; ++bit) {
        #pragma unroll
        for (int j = 0; j < 16; ++j)
            if (!(j & (1 << bit))) {
                int k = j | (1 << bit);
                float u = P[j], v = P[k];
                P[j] = u + v;
                P[k] = u - v;
            }
    }

    const int bp32 = ((lane ^ 32) << 2);
    float vout = 0.f;
#define MEAS(Q, RM)                                                           \
    { constexpr int RH_ = ((RM) >> 4) & 63;                                   \
      constexpr int RL_ = (RM) & 15;                                          \
      float v = P[RL_];                                                       \
      if (__popc(lane & RH_) & 1) v = -v;                                     \
      v += i2f(dppm<177>(f2i(v)));                 /* xor1  */                \
      v += i2f(dppm<78>(f2i(v)));                  /* xor2  */                \
      v += i2f(dppm<321>(dppm<27>(f2i(v))));       /* xor4 = 7^3 */           \
      v += i2f(dppm<320>(dppm<321>(f2i(v))));      /* xor8 = 15^7 */          \
      v += i2f(__builtin_amdgcn_ds_swizzle(f2i(v), (16 << 10) | 0x1F));       \
      v += i2f(__builtin_amdgcn_ds_bpermute(bp32, f2i(v)));                   \
      if (lane == (Q)) vout = v; }
    MEAS(0, 0x0CD) MEAS(1, 0x156) MEAS(2, 0x2AC) MEAS(3, 0x159)
    MEAS(4, 0x2B3) MEAS(5, 0x166) MEAS(6, 0x2CC) MEAS(7, 0x199)
    MEAS(8, 0x333) MEAS(9, 0x266)
#undef MEAS

    if (lane < NQ) out[b * NQ + lane] = vout;
}

extern "C" void kernel_launch(void* const* d_in, const int* in_sizes, int n_in,
                              void* d_out, int out_size, void* d_ws, size_t ws_size,
                              hipStream_t stream) {
    const float* x = (const float*)d_in[0];   // (4096, 10) f32
    const float* w = (const float*)d_in[1];   // (3, 10, 3) f32
    float* out = (float*)d_out;               // (4096, 10) f32
    const int B = in_sizes[0] / NQ;           // 4096
    qnn_kernel<<<B / 4, 256, 0, stream>>>(x, w, out);
}